// Round 1
// baseline (1931.306 us; speedup 1.0000x reference)
//
#include <hip/hip_runtime.h>
#include <hip/hip_bf16.h>
#include <cstdint>
#include <cmath>

typedef __bf16 bf16;
typedef __attribute__((ext_vector_type(8))) __bf16 bf16x8;
typedef __attribute__((ext_vector_type(4))) float f32x4;

// async global->LDS, 16B per lane, dest = wave-uniform base + lane*16
__device__ __forceinline__ void gload_lds16(const void* g, void* l) {
  __builtin_amdgcn_global_load_lds((__attribute__((address_space(1))) void*)g,
                                   (__attribute__((address_space(3))) void*)l,
                                   16, 0, 0);
}

// ---------------------------------------------------------------------------
// GEMM: C[M,N] = A[M,K] @ B[K,N], with Bt = B^T stored [N][K] bf16.
// m97 structure: 128x128 tile, BK=64, 4 waves (2x2), 16x16x32 bf16 MFMA.
// EPI 0: bf16 out. EPI 1: f32 out = acc + bias[col] + resid. EPI 2: f32 out = acc + resid.
// ---------------------------------------------------------------------------
template<int EPI>
__global__ __launch_bounds__(256) void gemm_bt(
    const bf16* __restrict__ A, const bf16* __restrict__ Bt, void* __restrict__ Cv,
    const float* __restrict__ bias, const float* __restrict__ resid,
    int M, int N, int K) {
  __shared__ bf16 As[128 * 64];
  __shared__ bf16 Bs[128 * 64];
  const int tid = threadIdx.x;
  const int wave = tid >> 6, lane = tid & 63;
  const int wr = wave >> 1, wc = wave & 1;
  const int tm = blockIdx.x, tn = blockIdx.y;
  const int srow = lane >> 3;          // row within 8-row chunk (64-elem rows)
  const int scol = (lane & 7) * 8;     // col element within row
  const bf16* Abase = A + (long)tm * 128 * K;
  const bf16* Bbase = Bt + (long)tn * 128 * K;
  f32x4 acc[4][4] = {};

  for (int k0 = 0; k0 < K; k0 += 64) {
    #pragma unroll
    for (int i = 0; i < 4; ++i) {
      const int c = wave + 4 * i;      // chunk 0..15, 1KB each (8 rows x 128B)
      const int row = c * 8 + srow;
      gload_lds16(Abase + (long)row * K + k0 + scol, As + c * 512);
      gload_lds16(Bbase + (long)row * K + k0 + scol, Bs + c * 512);
    }
    __syncthreads();
    #pragma unroll
    for (int kk = 0; kk < 64; kk += 32) {
      bf16x8 a[4], b[4];
      #pragma unroll
      for (int m = 0; m < 4; ++m)
        a[m] = *(const bf16x8*)(As + (wr * 64 + m * 16 + (lane & 15)) * 64 + kk + (lane >> 4) * 8);
      #pragma unroll
      for (int n = 0; n < 4; ++n)
        b[n] = *(const bf16x8*)(Bs + (wc * 64 + n * 16 + (lane & 15)) * 64 + kk + (lane >> 4) * 8);
      #pragma unroll
      for (int m = 0; m < 4; ++m)
        #pragma unroll
        for (int n = 0; n < 4; ++n)
          acc[m][n] = __builtin_amdgcn_mfma_f32_16x16x32_bf16(a[m], b[n], acc[m][n], 0, 0, 0);
    }
    __syncthreads();
  }

  const int lc = lane & 15, lr = (lane >> 4) * 4;
  #pragma unroll
  for (int m = 0; m < 4; ++m) {
    #pragma unroll
    for (int n = 0; n < 4; ++n) {
      const int col = tn * 128 + wc * 64 + n * 16 + lc;
      #pragma unroll
      for (int r = 0; r < 4; ++r) {
        const int row = tm * 128 + wr * 64 + m * 16 + lr + r;
        const long idx = (long)row * N + col;
        const float v = acc[m][n][r];
        if (EPI == 0)      ((bf16*)Cv)[idx] = (bf16)v;
        else if (EPI == 1) ((float*)Cv)[idx] = v + bias[col] + resid[idx];
        else               ((float*)Cv)[idx] = v + resid[idx];
      }
    }
  }
}

// ---------------------------------------------------------------------------
// RMSNorm: one block (256 thr) per row of [2048][4096] f32 -> bf16 out
// ---------------------------------------------------------------------------
__global__ __launch_bounds__(256) void rmsnorm_kernel(
    const float* __restrict__ X, const float* __restrict__ gamma,
    bf16* __restrict__ out, int D) {
  const int row = blockIdx.x;
  const float* xr = X + (long)row * D;
  float ss = 0.f;
  for (int i = threadIdx.x * 4; i < D; i += 1024) {
    float4 v = *(const float4*)(xr + i);
    ss += v.x * v.x + v.y * v.y + v.z * v.z + v.w * v.w;
  }
  #pragma unroll
  for (int off = 32; off; off >>= 1) ss += __shfl_down(ss, off, 64);
  __shared__ float wsum[4];
  if ((threadIdx.x & 63) == 0) wsum[threadIdx.x >> 6] = ss;
  __syncthreads();
  const float tot = wsum[0] + wsum[1] + wsum[2] + wsum[3];
  const float scale = rsqrtf(1e-7f + tot / (float)D);
  bf16* orow = out + (long)row * D;
  for (int i = threadIdx.x * 4; i < D; i += 1024) {
    float4 v = *(const float4*)(xr + i);
    float4 g = *(const float4*)(gamma + i);
    orow[i]     = (bf16)(v.x * scale * g.x);
    orow[i + 1] = (bf16)(v.y * scale * g.y);
    orow[i + 2] = (bf16)(v.z * scale * g.z);
    orow[i + 3] = (bf16)(v.w * scale * g.w);
  }
}

// ---------------------------------------------------------------------------
// Weight transpose + f32->bf16: in [R][C] f32 -> out [C][R] bf16. 32x32 tiles.
// ---------------------------------------------------------------------------
__global__ __launch_bounds__(256) void wtrans_kernel(
    const float* __restrict__ in, bf16* __restrict__ out, int R, int C) {
  __shared__ float t[32][33];
  const int bx = blockIdx.x, by = blockIdx.y;
  const int tx = threadIdx.x & 31, ty = threadIdx.x >> 5;  // 32x8
  #pragma unroll
  for (int i = 0; i < 32; i += 8)
    t[ty + i][tx] = in[(long)(by * 32 + ty + i) * C + bx * 32 + tx];
  __syncthreads();
  #pragma unroll
  for (int i = 0; i < 32; i += 8)
    out[(long)(bx * 32 + ty + i) * R + by * 32 + tx] = (bf16)t[tx][ty + i];
}

// ---------------------------------------------------------------------------
// RoPE tables: cos/sin [2048][64] f32
// ---------------------------------------------------------------------------
__global__ __launch_bounds__(256) void rope_table_kernel(float* __restrict__ cosT,
                                                         float* __restrict__ sinT) {
  const int idx = blockIdx.x * 256 + threadIdx.x;  // s*64 + i
  const int i = idx & 63, s = idx >> 6;
  const float inv = powf(10000.f, -(float)i / 64.f);
  const float ang = (float)s * inv;
  cosT[idx] = cosf(ang);
  sinT[idx] = sinf(ang);
}

// ---------------------------------------------------------------------------
// RoPE apply + reorder [s][h*128+d] -> [h][s][128] for q and k
// ---------------------------------------------------------------------------
__global__ __launch_bounds__(256) void rope_kernel(
    const bf16* __restrict__ qin, const bf16* __restrict__ kin,
    const float* __restrict__ cosT, const float* __restrict__ sinT,
    bf16* __restrict__ qout, bf16* __restrict__ kout) {
  const long idx = (long)blockIdx.x * 256 + threadIdx.x;  // total 2048*32*64
  const int i = (int)(idx & 63);
  const int h = (int)((idx >> 6) & 31);
  const int s = (int)(idx >> 11);
  const long in1 = (long)s * 4096 + h * 128 + i;
  const float c = cosT[s * 64 + i], sn = sinT[s * 64 + i];
  const long o1 = (long)h * 2048 * 128 + (long)s * 128 + i;
  const float q1 = (float)qin[in1], q2 = (float)qin[in1 + 64];
  qout[o1]      = (bf16)(q1 * c - q2 * sn);
  qout[o1 + 64] = (bf16)(q2 * c + q1 * sn);
  const float k1 = (float)kin[in1], k2 = (float)kin[in1 + 64];
  kout[o1]      = (bf16)(k1 * c - k2 * sn);
  kout[o1 + 64] = (bf16)(k2 * c + k1 * sn);
}

// ---------------------------------------------------------------------------
// V reorder-transpose: [s][h*128+d] -> vt [h][d=128][s=2048]
// ---------------------------------------------------------------------------
__global__ __launch_bounds__(256) void vtrans_kernel(const bf16* __restrict__ vin,
                                                     bf16* __restrict__ vt) {
  __shared__ bf16 t[64][65];
  const int h = blockIdx.z;
  const int s0 = blockIdx.x * 64, d0 = blockIdx.y * 64;
  const int tx = threadIdx.x & 63, ty = threadIdx.x >> 6;  // 64x4
  #pragma unroll
  for (int i = 0; i < 64; i += 4)
    t[ty + i][tx] = vin[(long)(s0 + ty + i) * 4096 + h * 128 + d0 + tx];
  __syncthreads();
  #pragma unroll
  for (int i = 0; i < 64; i += 4)
    vt[(long)h * 128 * 2048 + (long)(d0 + ty + i) * 2048 + s0 + tx] = t[tx][ty + i];
}

// ---------------------------------------------------------------------------
// Flash attention, causal. Block = (qb, head), 4 waves, wave owns 16 q-rows.
// q/k: [h][s][128]; vt: [h][128][s]; out: [s][4096] bf16.
// ---------------------------------------------------------------------------
__global__ __launch_bounds__(256) void attn_kernel(
    const bf16* __restrict__ qh, const bf16* __restrict__ kh,
    const bf16* __restrict__ vt, bf16* __restrict__ outb) {
  constexpr int S = 2048;
  const int qb = blockIdx.x, head = blockIdx.y;
  const int tid = threadIdx.x, wave = tid >> 6, lane = tid & 63;
  __shared__ bf16 Ks[64 * 128];   // [t][d]
  __shared__ bf16 Vs[128 * 64];   // [d][t]
  __shared__ bf16 Plds[4][16 * 64];  // per-wave [q][t]
  const bf16* qhh = qh + (long)head * S * 128;
  const bf16* khh = kh + (long)head * S * 128;
  const bf16* vth = vt + (long)head * 128 * S;

  const int l15 = lane & 15, l4 = lane >> 4;
  const int qrow = qb * 64 + wave * 16 + l15;
  bf16x8 qf[4];
  #pragma unroll
  for (int kf = 0; kf < 4; ++kf)
    qf[kf] = *(const bf16x8*)(qhh + (long)qrow * 128 + kf * 32 + l4 * 8);

  float m_r[4], l_r[4];
  #pragma unroll
  for (int r = 0; r < 4; ++r) { m_r[r] = -INFINITY; l_r[r] = 0.f; }
  f32x4 oacc[8] = {};
  const float scale = 0.08838834764831845f;  // 1/sqrt(128)

  for (int tb = 0; tb <= qb; ++tb) {
    #pragma unroll
    for (int i = 0; i < 4; ++i) {
      const int c = wave + 4 * i;  // 1KB chunks
      // K tile rows are 128 elems (256B): chunk = 4 rows
      gload_lds16(khh + (long)(tb * 64 + c * 4 + l4) * 128 + l15 * 8, Ks + c * 512);
      // V^T tile rows are 64 elems (128B): chunk = 8 rows
      gload_lds16(vth + (long)(c * 8 + (lane >> 3)) * S + tb * 64 + (lane & 7) * 8, Vs + c * 512);
    }
    __syncthreads();

    // S = Q K^T : lane holds S[q=(l>>4)*4+r][t=l&15 + 16*ft]
    f32x4 sf[4];
    #pragma unroll
    for (int ft = 0; ft < 4; ++ft) {
      f32x4 a = {};
      #pragma unroll
      for (int kf = 0; kf < 4; ++kf) {
        bf16x8 kfr = *(const bf16x8*)(Ks + (ft * 16 + l15) * 128 + kf * 32 + l4 * 8);
        a = __builtin_amdgcn_mfma_f32_16x16x32_bf16(qf[kf], kfr, a, 0, 0, 0);
      }
      #pragma unroll
      for (int r = 0; r < 4; ++r) sf[ft][r] = a[r] * scale;
    }
    if (tb == qb) {
      #pragma unroll
      for (int ft = 0; ft < 4; ++ft) {
        const int t_l = ft * 16 + l15;
        #pragma unroll
        for (int r = 0; r < 4; ++r)
          if (t_l > wave * 16 + l4 * 4 + r) sf[ft][r] = -INFINITY;
      }
    }
    // online softmax (reduce over t: in-reg over ft, cross-lane over l&15)
    float scl[4];
    #pragma unroll
    for (int r = 0; r < 4; ++r) {
      float mx = fmaxf(fmaxf(sf[0][r], sf[1][r]), fmaxf(sf[2][r], sf[3][r]));
      mx = fmaxf(mx, __shfl_xor(mx, 1, 64));
      mx = fmaxf(mx, __shfl_xor(mx, 2, 64));
      mx = fmaxf(mx, __shfl_xor(mx, 4, 64));
      mx = fmaxf(mx, __shfl_xor(mx, 8, 64));
      const float mnew = fmaxf(m_r[r], mx);
      scl[r] = __expf(m_r[r] - mnew);
      m_r[r] = mnew;
      float rs = 0.f;
      #pragma unroll
      for (int ft = 0; ft < 4; ++ft) {
        const float p = __expf(sf[ft][r] - mnew);
        sf[ft][r] = p;
        rs += p;
      }
      rs += __shfl_xor(rs, 1, 64);
      rs += __shfl_xor(rs, 2, 64);
      rs += __shfl_xor(rs, 4, 64);
      rs += __shfl_xor(rs, 8, 64);
      l_r[r] = l_r[r] * scl[r] + rs;
    }
    // P -> LDS in [q][t] (A-operand layout for PV)
    #pragma unroll
    for (int ft = 0; ft < 4; ++ft)
      #pragma unroll
      for (int r = 0; r < 4; ++r)
        Plds[wave][(l4 * 4 + r) * 64 + ft * 16 + l15] = (bf16)sf[ft][r];
    // rescale O then accumulate P @ V
    #pragma unroll
    for (int fd = 0; fd < 8; ++fd)
      #pragma unroll
      for (int r = 0; r < 4; ++r) oacc[fd][r] *= scl[r];
    #pragma unroll
    for (int fd = 0; fd < 8; ++fd) {
      #pragma unroll
      for (int kt = 0; kt < 2; ++kt) {
        bf16x8 pa = *(const bf16x8*)(&Plds[wave][l15 * 64 + kt * 32 + l4 * 8]);
        bf16x8 vb = *(const bf16x8*)(Vs + (fd * 16 + l15) * 64 + kt * 32 + l4 * 8);
        oacc[fd] = __builtin_amdgcn_mfma_f32_16x16x32_bf16(pa, vb, oacc[fd], 0, 0, 0);
      }
    }
    __syncthreads();
  }
  #pragma unroll
  for (int fd = 0; fd < 8; ++fd) {
    #pragma unroll
    for (int r = 0; r < 4; ++r) {
      const long row = qb * 64 + wave * 16 + l4 * 4 + r;
      outb[row * 4096 + head * 128 + fd * 16 + l15] = (bf16)(oacc[fd][r] / l_r[r]);
    }
  }
}

// ---------------------------------------------------------------------------
// SwiGLU: g = x1 * sigmoid(x1) * x2
// ---------------------------------------------------------------------------
__global__ __launch_bounds__(256) void swiglu_kernel(
    const bf16* __restrict__ x1, const bf16* __restrict__ x2,
    bf16* __restrict__ g, long n) {
  const long i = ((long)blockIdx.x * 256 + threadIdx.x) * 8;
  if (i >= n) return;
  bf16x8 a = *(const bf16x8*)(x1 + i);
  bf16x8 b = *(const bf16x8*)(x2 + i);
  bf16x8 o;
  #pragma unroll
  for (int j = 0; j < 8; ++j) {
    const float v = (float)a[j];
    const float s = v / (1.f + __expf(-v));
    o[j] = (bf16)(s * (float)b[j]);
  }
  *(bf16x8*)(g + i) = o;
}

// ---------------------------------------------------------------------------
extern "C" void kernel_launch(void* const* d_in, const int* in_sizes, int n_in,
                              void* d_out, int out_size, void* d_ws, size_t ws_size,
                              hipStream_t stream) {
  const float* X  = (const float*)d_in[0];
  const float* Wq = (const float*)d_in[1];
  const float* Wk = (const float*)d_in[2];
  const float* Wv = (const float*)d_in[3];
  const float* Wo = (const float*)d_in[4];
  const float* bo = (const float*)d_in[5];
  const float* g1 = (const float*)d_in[6];
  const float* g2 = (const float*)d_in[7];
  const float* W1 = (const float*)d_in[8];
  const float* W2 = (const float*)d_in[9];
  const float* W3 = (const float*)d_in[10];
  float* out = (float*)d_out;

  char* p = (char*)d_ws;
  auto alloc = [&](size_t bytes) {
    char* r = p;
    p += (bytes + 255) & ~(size_t)255;
    return r;
  };
  float* cosT = (float*)alloc(2048 * 64 * 4);
  float* sinT = (float*)alloc(2048 * 64 * 4);
  bf16* WqT = (bf16*)alloc(4096L * 4096 * 2);
  bf16* WkT = (bf16*)alloc(4096L * 4096 * 2);
  bf16* WvT = (bf16*)alloc(4096L * 4096 * 2);
  bf16* WoT = (bf16*)alloc(4096L * 4096 * 2);
  bf16* W1T = (bf16*)alloc(11008L * 4096 * 2);
  bf16* W2T = (bf16*)alloc(11008L * 4096 * 2);
  bf16* W3T = (bf16*)alloc(4096L * 11008 * 2);
  char* R1 = alloc(2 * 2048L * 11008 * 2);     // qtmp/ktmp/vtmp  then  x1/x2
  char* R2 = alloc(3 * 2048L * 4096 * 2);      // qh/kh/vt        then  g
  bf16* hbuf = (bf16*)alloc(2048L * 4096 * 2); // h               then  attnb
  bf16* h2   = (bf16*)alloc(2048L * 4096 * 2);
  float* X2  = (float*)alloc(2048L * 4096 * 4);

  bf16* qtmp = (bf16*)R1;
  bf16* ktmp = qtmp + 2048L * 4096;
  bf16* vtmp = ktmp + 2048L * 4096;
  bf16* x1 = (bf16*)R1;
  bf16* x2 = x1 + 2048L * 11008;
  bf16* qhB = (bf16*)R2;
  bf16* khB = qhB + 2048L * 4096;
  bf16* vtB = khB + 2048L * 4096;
  bf16* g = (bf16*)R2;
  bf16* attnb = hbuf;

  // RoPE tables + weight transposes/conversions
  rope_table_kernel<<<512, 256, 0, stream>>>(cosT, sinT);
  wtrans_kernel<<<dim3(128, 128), 256, 0, stream>>>(Wq, WqT, 4096, 4096);
  wtrans_kernel<<<dim3(128, 128), 256, 0, stream>>>(Wk, WkT, 4096, 4096);
  wtrans_kernel<<<dim3(128, 128), 256, 0, stream>>>(Wv, WvT, 4096, 4096);
  wtrans_kernel<<<dim3(128, 128), 256, 0, stream>>>(Wo, WoT, 4096, 4096);
  wtrans_kernel<<<dim3(344, 128), 256, 0, stream>>>(W1, W1T, 4096, 11008);
  wtrans_kernel<<<dim3(344, 128), 256, 0, stream>>>(W2, W2T, 4096, 11008);
  wtrans_kernel<<<dim3(128, 344), 256, 0, stream>>>(W3, W3T, 11008, 4096);

  // h = rmsnorm(X, g1)
  rmsnorm_kernel<<<2048, 256, 0, stream>>>(X, g1, hbuf, 4096);

  // q,k,v = h @ {Wq,Wk,Wv}
  gemm_bt<0><<<dim3(16, 32), 256, 0, stream>>>(hbuf, WqT, qtmp, nullptr, nullptr, 2048, 4096, 4096);
  gemm_bt<0><<<dim3(16, 32), 256, 0, stream>>>(hbuf, WkT, ktmp, nullptr, nullptr, 2048, 4096, 4096);
  gemm_bt<0><<<dim3(16, 32), 256, 0, stream>>>(hbuf, WvT, vtmp, nullptr, nullptr, 2048, 4096, 4096);

  // RoPE + head-major reorder; V transpose
  rope_kernel<<<16384, 256, 0, stream>>>(qtmp, ktmp, cosT, sinT, qhB, khB);
  vtrans_kernel<<<dim3(32, 2, 32), 256, 0, stream>>>(vtmp, vtB);

  // attention
  attn_kernel<<<dim3(32, 32), 256, 0, stream>>>(qhB, khB, vtB, attnb);

  // X2 = attn @ Wo + bo + X
  gemm_bt<1><<<dim3(16, 32), 256, 0, stream>>>(attnb, WoT, X2, bo, X, 2048, 4096, 4096);

  // h2 = rmsnorm(X2, g2)
  rmsnorm_kernel<<<2048, 256, 0, stream>>>(X2, g2, h2, 4096);

  // x1 = h2 @ W1 ; x2 = h2 @ W2
  gemm_bt<0><<<dim3(16, 86), 256, 0, stream>>>(h2, W1T, x1, nullptr, nullptr, 2048, 11008, 4096);
  gemm_bt<0><<<dim3(16, 86), 256, 0, stream>>>(h2, W2T, x2, nullptr, nullptr, 2048, 11008, 4096);

  // g = silu(x1) * x2
  swiglu_kernel<<<11008, 256, 0, stream>>>(x1, x2, g, 2048L * 11008);

  // out = g @ W3 + X2
  gemm_bt<2><<<dim3(16, 32), 256, 0, stream>>>(g, W3T, out, nullptr, X2, 2048, 4096, 11008);
}

// Round 2
// 1676.034 us; speedup vs baseline: 1.1523x; 1.1523x over previous
//
#include <hip/hip_runtime.h>
#include <hip/hip_bf16.h>
#include <cstdint>
#include <cmath>

typedef __bf16 bf16;
typedef __attribute__((ext_vector_type(8))) __bf16 bf16x8;
typedef __attribute__((ext_vector_type(4))) float f32x4;

// async global->LDS, 16B per lane, dest = wave-uniform base (+ lane*16 by HW)
__device__ __forceinline__ void gload_lds16(const void* g, void* l) {
  __builtin_amdgcn_global_load_lds((__attribute__((address_space(1))) void*)g,
                                   (__attribute__((address_space(3))) void*)l,
                                   16, 0, 0);
}

// ---------------------------------------------------------------------------
// 256x256 8-phase GEMM (T1+T2+T3+T4+T5), BK=64, 8 waves (2Mx4N), 128KiB LDS.
// C[M,N] = A[M,K] @ Bt^T  (Bt is B^T stored [N][K] bf16).
// LDS map (byte): buf*65536 + isB*32768 + half*16384 + row*128 + chunk*16,
//   half = 128 rows; chunk swizzle: stored_chunk = logical_chunk ^ (row&7).
// Race-free ledger: A-halves(tile g) last read in phase C, B-halves in phase B;
// stages: A: A-h0(g+1), B: A-h1(g+1)  (into buf[g^1], A dead since C(g-1))
//         C: B-h0(g+2), D: B-h1(g+2)  (into buf[g],   B dead after B(g))
// vmcnt(4) at end of D retires tile g+1 fully (leaves g+2's 4 B-loads in flight).
// ---------------------------------------------------------------------------
template<int EPI>
__global__ __launch_bounds__(512, 2) void gemm8p(
    const bf16* __restrict__ A, const bf16* __restrict__ Bt, void* __restrict__ Cv,
    const float* __restrict__ bias, const float* __restrict__ resid,
    int M, int N, int K, int gm) {
  extern __shared__ char lds[];
  const int tid = threadIdx.x;
  const int wave = tid >> 6, lane = tid & 63;
  const int wr = wave >> 2, wc = wave & 3;
  const int l15 = lane & 15, l4 = lane >> 4;
  // bijective XCD swizzle (m204 variant)
  const int nwg = gridDim.x;
  const int qq = nwg >> 3, rr8 = nwg & 7;
  const int xcd = blockIdx.x & 7, sidx = blockIdx.x >> 3;
  const int wgid = (xcd < rr8 ? xcd * (qq + 1) : rr8 * (qq + 1) + (xcd - rr8) * qq) + sidx;
  const int tm = wgid % gm, tn = wgid / gm;
  const long brow = (long)tm * 256, bcol = (long)tn * 256;
  const int NT = K >> 6;
  const bf16* Ab = A + brow * K;
  const bf16* Bb = Bt + bcol * K;

  f32x4 acc[8][4];
  #pragma unroll
  for (int i = 0; i < 8; ++i)
    #pragma unroll
    for (int j = 0; j < 4; ++j) acc[i][j] = (f32x4){0.f, 0.f, 0.f, 0.f};

  bf16x8 a[4][2], b0[2][2], b1[2][2];

  const int s_r = tid >> 3;    // stage row (i=0); i=1 adds 64
  const int s_c0 = tid & 7;    // stage chunk (linear LDS dest)

  #define STAGE(T, AB, H) do {                                                  \
    const bf16* rb_ = ((AB) ? Bb : Ab) + (long)((H) * 128) * K + (T) * 64;      \
    char* lb_ = lds + ((((T) & 1) * 65536) + (AB) * 32768 + (H) * 16384 + wave * 1024); \
    _Pragma("unroll")                                                           \
    for (int i_ = 0; i_ < 2; ++i_) {                                            \
      int r_ = s_r + i_ * 64;                                                   \
      int c_ = s_c0 ^ (r_ & 7);   /* inverse-swizzled global source */          \
      gload_lds16(rb_ + (long)r_ * K + c_ * 8, lb_ + i_ * 8192);                \
    } } while (0)

  #define LDA(MH) do {                                                          \
    _Pragma("unroll") for (int mf = 0; mf < 4; ++mf) {                          \
      int rl = wr * 128 + (MH) * 64 + mf * 16 + l15;                            \
      int base = ((g & 1) * 65536) + (rl >> 7) * 16384 + (rl & 127) * 128;      \
      _Pragma("unroll") for (int ks = 0; ks < 2; ++ks) {                        \
        int kc = (ks * 4 + l4) ^ (rl & 7);                                      \
        a[mf][ks] = *(const bf16x8*)(lds + base + kc * 16);                     \
      } } } while (0)

  #define LDB(BR, NH) do {                                                     \
    _Pragma("unroll") for (int nf = 0; nf < 2; ++nf) {                          \
      int rl = wc * 64 + (NH) * 32 + nf * 16 + l15;                             \
      int base = ((g & 1) * 65536) + 32768 + (rl >> 7) * 16384 + (rl & 127) * 128; \
      _Pragma("unroll") for (int ks = 0; ks < 2; ++ks) {                        \
        int kc = (ks * 4 + l4) ^ (rl & 7);                                      \
        BR[nf][ks] = *(const bf16x8*)(lds + base + kc * 16);                    \
      } } } while (0)

  #define QMFMA(BR, I0, J0) do {                                               \
    _Pragma("unroll") for (int ks = 0; ks < 2; ++ks)                            \
    _Pragma("unroll") for (int mf = 0; mf < 4; ++mf)                            \
    _Pragma("unroll") for (int nf = 0; nf < 2; ++nf)                            \
      acc[(I0) + mf][(J0) + nf] = __builtin_amdgcn_mfma_f32_16x16x32_bf16(      \
          a[mf][ks], BR[nf][ks], acc[(I0) + mf][(J0) + nf], 0, 0, 0);           \
  } while (0)

  // prologue: tile0 fully + tile1 B-halves; wait tile0 (leave t1.B in flight)
  STAGE(0, 0, 0); STAGE(0, 0, 1); STAGE(0, 1, 0); STAGE(0, 1, 1);
  if (NT > 1) { STAGE(1, 1, 0); STAGE(1, 1, 1); }
  asm volatile("s_waitcnt vmcnt(4)" ::: "memory");
  __builtin_amdgcn_s_barrier();

  for (int g = 0; g < NT; ++g) {
    // Phase A: q(m0,n0)
    LDA(0); LDB(b0, 0);
    if (g + 1 < NT) STAGE(g + 1, 0, 0);
    __builtin_amdgcn_s_barrier();
    __builtin_amdgcn_s_setprio(1);
    QMFMA(b0, 0, 0);
    __builtin_amdgcn_s_setprio(0);
    __builtin_amdgcn_s_barrier();
    // Phase B: q(m0,n1)
    LDB(b1, 1);
    if (g + 1 < NT) STAGE(g + 1, 0, 1);
    __builtin_amdgcn_s_barrier();
    __builtin_amdgcn_s_setprio(1);
    QMFMA(b1, 0, 2);
    __builtin_amdgcn_s_setprio(0);
    __builtin_amdgcn_s_barrier();
    // Phase C: q(m1,n0)
    LDA(1);
    if (g + 2 < NT) STAGE(g + 2, 1, 0);
    __builtin_amdgcn_s_barrier();
    __builtin_amdgcn_s_setprio(1);
    QMFMA(b0, 4, 0);
    __builtin_amdgcn_s_setprio(0);
    __builtin_amdgcn_s_barrier();
    // Phase D: q(m1,n1)
    if (g + 2 < NT) STAGE(g + 2, 1, 1);
    __builtin_amdgcn_s_barrier();
    __builtin_amdgcn_s_setprio(1);
    QMFMA(b1, 4, 2);
    __builtin_amdgcn_s_setprio(0);
    if (g + 2 < NT)      asm volatile("s_waitcnt vmcnt(4)" ::: "memory");
    else if (g + 1 < NT) asm volatile("s_waitcnt vmcnt(0)" ::: "memory");
    __builtin_amdgcn_s_barrier();
  }

  #pragma unroll
  for (int i = 0; i < 8; ++i) {
    const long row = brow + wr * 128 + i * 16 + l4 * 4;
    #pragma unroll
    for (int j = 0; j < 4; ++j) {
      const long col = bcol + wc * 64 + j * 16 + l15;
      #pragma unroll
      for (int rj = 0; rj < 4; ++rj) {
        const long idx = (row + rj) * N + col;
        const float v = acc[i][j][rj];
        if (EPI == 0)      ((bf16*)Cv)[idx] = (bf16)v;
        else if (EPI == 1) ((float*)Cv)[idx] = v + bias[col] + resid[idx];
        else               ((float*)Cv)[idx] = v + resid[idx];
      }
    }
  }
  #undef STAGE
  #undef LDA
  #undef LDB
  #undef QMFMA
}

// ---------------------------------------------------------------------------
// RMSNorm: one block per row of [2048][4096] f32 -> bf16
// ---------------------------------------------------------------------------
__global__ __launch_bounds__(256) void rmsnorm_kernel(
    const float* __restrict__ X, const float* __restrict__ gamma,
    bf16* __restrict__ out, int D) {
  const int row = blockIdx.x;
  const float* xr = X + (long)row * D;
  float ss = 0.f;
  for (int i = threadIdx.x * 4; i < D; i += 1024) {
    float4 v = *(const float4*)(xr + i);
    ss += v.x * v.x + v.y * v.y + v.z * v.z + v.w * v.w;
  }
  #pragma unroll
  for (int off = 32; off; off >>= 1) ss += __shfl_down(ss, off, 64);
  __shared__ float wsum[4];
  if ((threadIdx.x & 63) == 0) wsum[threadIdx.x >> 6] = ss;
  __syncthreads();
  const float tot = wsum[0] + wsum[1] + wsum[2] + wsum[3];
  const float scale = rsqrtf(1e-7f + tot / (float)D);
  bf16* orow = out + (long)row * D;
  for (int i = threadIdx.x * 4; i < D; i += 1024) {
    float4 v = *(const float4*)(xr + i);
    float4 g = *(const float4*)(gamma + i);
    orow[i]     = (bf16)(v.x * scale * g.x);
    orow[i + 1] = (bf16)(v.y * scale * g.y);
    orow[i + 2] = (bf16)(v.z * scale * g.z);
    orow[i + 3] = (bf16)(v.w * scale * g.w);
  }
}

// ---------------------------------------------------------------------------
// Weight transpose + f32->bf16: in [R][C] f32 -> out [C][R] bf16
// ---------------------------------------------------------------------------
__global__ __launch_bounds__(256) void wtrans_kernel(
    const float* __restrict__ in, bf16* __restrict__ out, int R, int C) {
  __shared__ float t[32][33];
  const int bx = blockIdx.x, by = blockIdx.y;
  const int tx = threadIdx.x & 31, ty = threadIdx.x >> 5;
  #pragma unroll
  for (int i = 0; i < 32; i += 8)
    t[ty + i][tx] = in[(long)(by * 32 + ty + i) * C + bx * 32 + tx];
  __syncthreads();
  #pragma unroll
  for (int i = 0; i < 32; i += 8)
    out[(long)(bx * 32 + ty + i) * R + by * 32 + tx] = (bf16)t[tx][ty + i];
}

// ---------------------------------------------------------------------------
__global__ __launch_bounds__(256) void rope_table_kernel(float* __restrict__ cosT,
                                                         float* __restrict__ sinT) {
  const int idx = blockIdx.x * 256 + threadIdx.x;
  const int i = idx & 63, s = idx >> 6;
  const float inv = powf(10000.f, -(float)i / 64.f);
  const float ang = (float)s * inv;
  cosT[idx] = cosf(ang);
  sinT[idx] = sinf(ang);
}

// ---------------------------------------------------------------------------
// RoPE apply + reorder: qkv [s][12288] (q cols 0.., k cols 4096..) -> [h][s][128]
// ---------------------------------------------------------------------------
__global__ __launch_bounds__(256) void rope_kernel(
    const bf16* __restrict__ qkv,
    const float* __restrict__ cosT, const float* __restrict__ sinT,
    bf16* __restrict__ qout, bf16* __restrict__ kout) {
  const long idx = (long)blockIdx.x * 256 + threadIdx.x;  // 2048*32*64
  const int i = (int)(idx & 63);
  const int h = (int)((idx >> 6) & 31);
  const int s = (int)(idx >> 11);
  const long inq = (long)s * 12288 + h * 128 + i;
  const float c = cosT[s * 64 + i], sn = sinT[s * 64 + i];
  const long o1 = (long)h * 2048 * 128 + (long)s * 128 + i;
  const float q1 = (float)qkv[inq], q2 = (float)qkv[inq + 64];
  qout[o1]      = (bf16)(q1 * c - q2 * sn);
  qout[o1 + 64] = (bf16)(q2 * c + q1 * sn);
  const float k1 = (float)qkv[inq + 4096], k2 = (float)qkv[inq + 4096 + 64];
  kout[o1]      = (bf16)(k1 * c - k2 * sn);
  kout[o1 + 64] = (bf16)(k2 * c + k1 * sn);
}

// ---------------------------------------------------------------------------
// V reorder-transpose: qkv cols 8192.. [s][12288] -> vt [h][128][2048]
// ---------------------------------------------------------------------------
__global__ __launch_bounds__(256) void vtrans_kernel(const bf16* __restrict__ qkv,
                                                     bf16* __restrict__ vt) {
  __shared__ bf16 t[64][65];
  const int h = blockIdx.z;
  const int s0 = blockIdx.x * 64, d0 = blockIdx.y * 64;
  const int tx = threadIdx.x & 63, ty = threadIdx.x >> 6;
  #pragma unroll
  for (int i = 0; i < 64; i += 4)
    t[ty + i][tx] = qkv[(long)(s0 + ty + i) * 12288 + 8192 + h * 128 + d0 + tx];
  __syncthreads();
  #pragma unroll
  for (int i = 0; i < 64; i += 4)
    vt[(long)h * 128 * 2048 + (long)(d0 + ty + i) * 2048 + s0 + tx] = t[tx][ty + i];
}

// ---------------------------------------------------------------------------
// Flash attention, causal. Block=(qb,head), 4 waves x 16 q-rows.
// ---------------------------------------------------------------------------
__global__ __launch_bounds__(256) void attn_kernel(
    const bf16* __restrict__ qh, const bf16* __restrict__ kh,
    const bf16* __restrict__ vt, bf16* __restrict__ outb) {
  constexpr int S = 2048;
  const int qb = blockIdx.x, head = blockIdx.y;
  const int tid = threadIdx.x, wave = tid >> 6, lane = tid & 63;
  __shared__ bf16 Ks[64 * 128];
  __shared__ bf16 Vs[128 * 64];
  __shared__ bf16 Plds[4][16 * 64];
  const bf16* qhh = qh + (long)head * S * 128;
  const bf16* khh = kh + (long)head * S * 128;
  const bf16* vth = vt + (long)head * 128 * S;

  const int l15 = lane & 15, l4 = lane >> 4;
  const int qrow = qb * 64 + wave * 16 + l15;
  bf16x8 qf[4];
  #pragma unroll
  for (int kf = 0; kf < 4; ++kf)
    qf[kf] = *(const bf16x8*)(qhh + (long)qrow * 128 + kf * 32 + l4 * 8);

  float m_r[4], l_r[4];
  #pragma unroll
  for (int r = 0; r < 4; ++r) { m_r[r] = -INFINITY; l_r[r] = 0.f; }
  f32x4 oacc[8] = {};
  const float scale = 0.08838834764831845f;

  for (int tb = 0; tb <= qb; ++tb) {
    #pragma unroll
    for (int i = 0; i < 4; ++i) {
      const int c = wave + 4 * i;
      gload_lds16(khh + (long)(tb * 64 + c * 4 + l4) * 128 + l15 * 8, Ks + c * 512);
      gload_lds16(vth + (long)(c * 8 + (lane >> 3)) * S + tb * 64 + (lane & 7) * 8, Vs + c * 512);
    }
    __syncthreads();

    f32x4 sf[4];
    #pragma unroll
    for (int ft = 0; ft < 4; ++ft) {
      f32x4 acn = {};
      #pragma unroll
      for (int kf = 0; kf < 4; ++kf) {
        bf16x8 kfr = *(const bf16x8*)(Ks + (ft * 16 + l15) * 128 + kf * 32 + l4 * 8);
        acn = __builtin_amdgcn_mfma_f32_16x16x32_bf16(qf[kf], kfr, acn, 0, 0, 0);
      }
      #pragma unroll
      for (int r = 0; r < 4; ++r) sf[ft][r] = acn[r] * scale;
    }
    if (tb == qb) {
      #pragma unroll
      for (int ft = 0; ft < 4; ++ft) {
        const int t_l = ft * 16 + l15;
        #pragma unroll
        for (int r = 0; r < 4; ++r)
          if (t_l > wave * 16 + l4 * 4 + r) sf[ft][r] = -INFINITY;
      }
    }
    float scl[4];
    #pragma unroll
    for (int r = 0; r < 4; ++r) {
      float mx = fmaxf(fmaxf(sf[0][r], sf[1][r]), fmaxf(sf[2][r], sf[3][r]));
      mx = fmaxf(mx, __shfl_xor(mx, 1, 64));
      mx = fmaxf(mx, __shfl_xor(mx, 2, 64));
      mx = fmaxf(mx, __shfl_xor(mx, 4, 64));
      mx = fmaxf(mx, __shfl_xor(mx, 8, 64));
      const float mnew = fmaxf(m_r[r], mx);
      scl[r] = __expf(m_r[r] - mnew);
      m_r[r] = mnew;
      float rs = 0.f;
      #pragma unroll
      for (int ft = 0; ft < 4; ++ft) {
        const float pexp = __expf(sf[ft][r] - mnew);
        sf[ft][r] = pexp;
        rs += pexp;
      }
      rs += __shfl_xor(rs, 1, 64);
      rs += __shfl_xor(rs, 2, 64);
      rs += __shfl_xor(rs, 4, 64);
      rs += __shfl_xor(rs, 8, 64);
      l_r[r] = l_r[r] * scl[r] + rs;
    }
    #pragma unroll
    for (int ft = 0; ft < 4; ++ft)
      #pragma unroll
      for (int r = 0; r < 4; ++r)
        Plds[wave][(l4 * 4 + r) * 64 + ft * 16 + l15] = (bf16)sf[ft][r];
    #pragma unroll
    for (int fd = 0; fd < 8; ++fd)
      #pragma unroll
      for (int r = 0; r < 4; ++r) oacc[fd][r] *= scl[r];
    #pragma unroll
    for (int fd = 0; fd < 8; ++fd) {
      #pragma unroll
      for (int kt = 0; kt < 2; ++kt) {
        bf16x8 pa = *(const bf16x8*)(&Plds[wave][l15 * 64 + kt * 32 + l4 * 8]);
        bf16x8 vb = *(const bf16x8*)(Vs + (fd * 16 + l15) * 64 + kt * 32 + l4 * 8);
        oacc[fd] = __builtin_amdgcn_mfma_f32_16x16x32_bf16(pa, vb, oacc[fd], 0, 0, 0);
      }
    }
    __syncthreads();
  }
  #pragma unroll
  for (int fd = 0; fd < 8; ++fd) {
    #pragma unroll
    for (int r = 0; r < 4; ++r) {
      const long row = qb * 64 + wave * 16 + l4 * 4 + r;
      outb[row * 4096 + head * 128 + fd * 16 + l15] = (bf16)(oacc[fd][r] / l_r[r]);
    }
  }
}

// ---------------------------------------------------------------------------
__global__ __launch_bounds__(256) void swiglu_kernel(
    const bf16* __restrict__ x1, const bf16* __restrict__ x2,
    bf16* __restrict__ g, long n) {
  const long i = ((long)blockIdx.x * 256 + threadIdx.x) * 8;
  if (i >= n) return;
  bf16x8 av = *(const bf16x8*)(x1 + i);
  bf16x8 bv = *(const bf16x8*)(x2 + i);
  bf16x8 o;
  #pragma unroll
  for (int j = 0; j < 8; ++j) {
    const float v = (float)av[j];
    const float s = v / (1.f + __expf(-v));
    o[j] = (bf16)(s * (float)bv[j]);
  }
  *(bf16x8*)(g + i) = o;
}

// ---------------------------------------------------------------------------
extern "C" void kernel_launch(void* const* d_in, const int* in_sizes, int n_in,
                              void* d_out, int out_size, void* d_ws, size_t ws_size,
                              hipStream_t stream) {
  const float* X  = (const float*)d_in[0];
  const float* Wq = (const float*)d_in[1];
  const float* Wk = (const float*)d_in[2];
  const float* Wv = (const float*)d_in[3];
  const float* Wo = (const float*)d_in[4];
  const float* bo = (const float*)d_in[5];
  const float* g1 = (const float*)d_in[6];
  const float* g2 = (const float*)d_in[7];
  const float* W1 = (const float*)d_in[8];
  const float* W2 = (const float*)d_in[9];
  const float* W3 = (const float*)d_in[10];
  float* out = (float*)d_out;

  hipFuncSetAttribute((const void*)gemm8p<0>, hipFuncAttributeMaxDynamicSharedMemorySize, 131072);
  hipFuncSetAttribute((const void*)gemm8p<1>, hipFuncAttributeMaxDynamicSharedMemorySize, 131072);
  hipFuncSetAttribute((const void*)gemm8p<2>, hipFuncAttributeMaxDynamicSharedMemorySize, 131072);

  char* p = (char*)d_ws;
  auto alloc = [&](size_t bytes) {
    char* r = p;
    p += (bytes + 255) & ~(size_t)255;
    return r;
  };
  float* cosT = (float*)alloc(2048 * 64 * 4);
  float* sinT = (float*)alloc(2048 * 64 * 4);
  bf16* WqkvT = (bf16*)alloc(12288L * 4096 * 2);   // [12288][4096], q/k/v stacked
  bf16* WoT = (bf16*)alloc(4096L * 4096 * 2);
  bf16* W1T = (bf16*)alloc(11008L * 4096 * 2);
  bf16* W2T = (bf16*)alloc(11008L * 4096 * 2);
  bf16* W3T = (bf16*)alloc(4096L * 11008 * 2);
  char* BIG = alloc(2048L * 12288 * 2 + 3 * 2048L * 4096 * 2);  // qkv+qh/kh/vt, then x1/x2
  bf16* hbuf = (bf16*)alloc(2048L * 4096 * 2);  // h, then attnb
  bf16* h2   = (bf16*)alloc(2048L * 4096 * 2);
  float* X2  = (float*)alloc(2048L * 4096 * 4);

  bf16* qkv = (bf16*)BIG;
  bf16* qhB = qkv + 2048L * 12288;
  bf16* khB = qhB + 2048L * 4096;
  bf16* vtB = khB + 2048L * 4096;
  bf16* x1 = (bf16*)BIG;
  bf16* x2 = x1 + 2048L * 11008;
  bf16* gsw = (bf16*)WqkvT;   // reuse (dead after QKV GEMM)
  bf16* attnb = hbuf;

  rope_table_kernel<<<512, 256, 0, stream>>>(cosT, sinT);
  wtrans_kernel<<<dim3(128, 128), 256, 0, stream>>>(Wq, WqkvT, 4096, 4096);
  wtrans_kernel<<<dim3(128, 128), 256, 0, stream>>>(Wk, WqkvT + 4096L * 4096, 4096, 4096);
  wtrans_kernel<<<dim3(128, 128), 256, 0, stream>>>(Wv, WqkvT + 2 * 4096L * 4096, 4096, 4096);
  wtrans_kernel<<<dim3(128, 128), 256, 0, stream>>>(Wo, WoT, 4096, 4096);
  wtrans_kernel<<<dim3(344, 128), 256, 0, stream>>>(W1, W1T, 4096, 11008);
  wtrans_kernel<<<dim3(344, 128), 256, 0, stream>>>(W2, W2T, 4096, 11008);
  wtrans_kernel<<<dim3(128, 344), 256, 0, stream>>>(W3, W3T, 11008, 4096);

  rmsnorm_kernel<<<2048, 256, 0, stream>>>(X, g1, hbuf, 4096);

  // qkv = h @ [Wq|Wk|Wv]
  gemm8p<0><<<8 * 48, 512, 131072, stream>>>(hbuf, WqkvT, qkv, nullptr, nullptr, 2048, 12288, 4096, 8);

  rope_kernel<<<16384, 256, 0, stream>>>(qkv, cosT, sinT, qhB, khB);
  vtrans_kernel<<<dim3(32, 2, 32), 256, 0, stream>>>(qkv, vtB);

  attn_kernel<<<dim3(32, 32), 256, 0, stream>>>(qhB, khB, vtB, attnb);

  // X2 = attn @ Wo + bo + X
  gemm8p<1><<<8 * 16, 512, 131072, stream>>>(attnb, WoT, X2, bo, X, 2048, 4096, 4096, 8);

  rmsnorm_kernel<<<2048, 256, 0, stream>>>(X2, g2, h2, 4096);

  gemm8p<0><<<8 * 43, 512, 131072, stream>>>(h2, W1T, x1, nullptr, nullptr, 2048, 11008, 4096, 8);
  gemm8p<0><<<8 * 43, 512, 131072, stream>>>(h2, W2T, x2, nullptr, nullptr, 2048, 11008, 4096, 8);

  swiglu_kernel<<<11008, 256, 0, stream>>>(x1, x2, gsw, 2048L * 11008);

  // out = g @ W3 + X2
  gemm8p<2><<<8 * 16, 512, 131072, stream>>>(gsw, W3T, out, nullptr, X2, 2048, 4096, 11008, 8);
}

// Round 4
// 1489.352 us; speedup vs baseline: 1.2967x; 1.1253x over previous
//
#include <hip/hip_runtime.h>
#include <hip/hip_bf16.h>
#include <cstdint>
#include <cmath>

typedef __bf16 bf16;
typedef __attribute__((ext_vector_type(8))) __bf16 bf16x8;
typedef __attribute__((ext_vector_type(4))) float f32x4;

// async global->LDS, 16B per lane, dest = wave-uniform base (+ lane*16 by HW)
__device__ __forceinline__ void gload_lds16(const void* g, void* l) {
  __builtin_amdgcn_global_load_lds((__attribute__((address_space(1))) void*)g,
                                   (__attribute__((address_space(3))) void*)l,
                                   16, 0, 0);
}

// ---------------------------------------------------------------------------
// Drift GEMM: BM x 256 tile, BK=64, 8 waves (2M x 4N), double-buffered LDS,
// ONE __syncthreads per K-tile, full-tile prefetch front-loaded (issued ~2500
// cycles before the vmcnt drain at the next barrier -> drain is cheap).
// C[M,N] = A[M,K] @ Bt^T  (Bt stored [N][K] bf16).
// LDS (bytes): buf*BUFS + {A:0, B:ASZ} + row*128 + chunk*16,
//   stored chunk = logical chunk ^ (row&7)  (conflict-free b128 reads).
// EPI 0: bf16 out. EPI 1: f32 = acc+bias[col]+resid. EPI 2: f32 = acc+resid.
// ---------------------------------------------------------------------------
template<int BM, int EPI>
__global__ __launch_bounds__(512, 2) void gemmd(
    const bf16* __restrict__ A, const bf16* __restrict__ Bt, void* __restrict__ Cv,
    const float* __restrict__ bias, const float* __restrict__ resid,
    int M, int N, int K, int gm) {
  extern __shared__ char lds[];
  constexpr int ASZ = BM * 128;      // A region bytes (BM rows x 128B)
  constexpr int BUFS = ASZ + 32768;  // per-buffer stride (B is 256 rows)
  constexpr int WM = BM / 32;        // m-frags per wave
  constexpr int AH = WM / 4;         // a-half loop count
  constexpr int LA = BM / 64;        // A stage loads per thread

  const int tid = threadIdx.x;
  const int wave = tid >> 6, lane = tid & 63;
  const int wr = wave >> 2, wc = wave & 3;
  const int l15 = lane & 15, l4 = lane >> 4;
  // XCD-aware swizzle (grids are multiples of 8)
  const int qq = gridDim.x >> 3;
  const int wgid = (blockIdx.x & 7) * qq + (blockIdx.x >> 3);
  const int tm = wgid % gm, tn = wgid / gm;
  const long brow = (long)tm * BM, bcol = (long)tn * 256;
  const int NT = K >> 6;
  const bf16* Ab = A + brow * K;
  const bf16* Bb = Bt + bcol * K;

  f32x4 acc[WM][4];
  #pragma unroll
  for (int i = 0; i < WM; ++i)
    #pragma unroll
    for (int j = 0; j < 4; ++j) acc[i][j] = (f32x4){0.f, 0.f, 0.f, 0.f};

  bf16x8 a[4][2], b[4][2];

  auto stage = [&](int T) {
    const long kofs = (long)T << 6;
    char* wb = lds + (T & 1) * BUFS;
    #pragma unroll
    for (int i = 0; i < LA; ++i) {
      const int slot = i * 512 + tid, r = slot >> 3, c0 = slot & 7;
      gload_lds16(Ab + (long)r * K + kofs + ((c0 ^ (r & 7)) << 3), wb + slot * 16);
    }
    #pragma unroll
    for (int i = 0; i < 4; ++i) {
      const int slot = i * 512 + tid, r = slot >> 3, c0 = slot & 7;
      gload_lds16(Bb + (long)r * K + kofs + ((c0 ^ (r & 7)) << 3), wb + ASZ + slot * 16);
    }
  };

  stage(0);
  __syncthreads();

  for (int g = 0; g < NT; ++g) {
    const int pg = (g & 1) * BUFS;
    if (g + 1 < NT) stage(g + 1);   // writes opposite buffer; fenced by barrier
    #pragma unroll
    for (int nf = 0; nf < 4; ++nf)
      #pragma unroll
      for (int ks = 0; ks < 2; ++ks) {
        const int r = wc * 64 + nf * 16 + l15;
        b[nf][ks] = *(const bf16x8*)(lds + pg + ASZ + r * 128 + (((ks * 4 + l4) ^ (r & 7)) << 4));
      }
    #pragma unroll
    for (int ah = 0; ah < AH; ++ah) {
      #pragma unroll
      for (int mf = 0; mf < 4; ++mf)
        #pragma unroll
        for (int ks = 0; ks < 2; ++ks) {
          const int r = wr * (BM / 2) + ah * 64 + mf * 16 + l15;
          a[mf][ks] = *(const bf16x8*)(lds + pg + r * 128 + (((ks * 4 + l4) ^ (r & 7)) << 4));
        }
      #pragma unroll
      for (int ks = 0; ks < 2; ++ks)
        #pragma unroll
        for (int mf = 0; mf < 4; ++mf)
          #pragma unroll
          for (int nf = 0; nf < 4; ++nf)
            acc[ah * 4 + mf][nf] = __builtin_amdgcn_mfma_f32_16x16x32_bf16(
                a[mf][ks], b[nf][ks], acc[ah * 4 + mf][nf], 0, 0, 0);
    }
    __syncthreads();
  }

  #pragma unroll
  for (int i = 0; i < WM; ++i) {
    const long row = brow + wr * (BM / 2) + (i >> 2) * 64 + (i & 3) * 16 + l4 * 4;
    #pragma unroll
    for (int j = 0; j < 4; ++j) {
      const long col = bcol + wc * 64 + j * 16 + l15;
      #pragma unroll
      for (int rj = 0; rj < 4; ++rj) {
        const long idx = (row + rj) * N + col;
        const float v = acc[i][j][rj];
        if (EPI == 0)      ((bf16*)Cv)[idx] = (bf16)v;
        else if (EPI == 1) ((float*)Cv)[idx] = v + bias[col] + resid[idx];
        else               ((float*)Cv)[idx] = v + resid[idx];
      }
    }
  }
}

// ---------------------------------------------------------------------------
// RMSNorm: one block per row of [2048][4096] f32 -> bf16
// ---------------------------------------------------------------------------
__global__ __launch_bounds__(256) void rmsnorm_kernel(
    const float* __restrict__ X, const float* __restrict__ gamma,
    bf16* __restrict__ out, int D) {
  const int row = blockIdx.x;
  const float* xr = X + (long)row * D;
  float ss = 0.f;
  for (int i = threadIdx.x * 4; i < D; i += 1024) {
    float4 v = *(const float4*)(xr + i);
    ss += v.x * v.x + v.y * v.y + v.z * v.z + v.w * v.w;
  }
  #pragma unroll
  for (int off = 32; off; off >>= 1) ss += __shfl_down(ss, off, 64);
  __shared__ float wsum[4];
  if ((threadIdx.x & 63) == 0) wsum[threadIdx.x >> 6] = ss;
  __syncthreads();
  const float tot = wsum[0] + wsum[1] + wsum[2] + wsum[3];
  const float scale = rsqrtf(1e-7f + tot / (float)D);
  bf16* orow = out + (long)row * D;
  for (int i = threadIdx.x * 4; i < D; i += 1024) {
    float4 v = *(const float4*)(xr + i);
    float4 g = *(const float4*)(gamma + i);
    orow[i]     = (bf16)(v.x * scale * g.x);
    orow[i + 1] = (bf16)(v.y * scale * g.y);
    orow[i + 2] = (bf16)(v.z * scale * g.z);
    orow[i + 3] = (bf16)(v.w * scale * g.w);
  }
}

// ---------------------------------------------------------------------------
// Weight transpose + f32->bf16: in [R][C] f32 -> out [C][R] bf16
// ---------------------------------------------------------------------------
__global__ __launch_bounds__(256) void wtrans_kernel(
    const float* __restrict__ in, bf16* __restrict__ out, int R, int C) {
  __shared__ float t[32][33];
  const int bx = blockIdx.x, by = blockIdx.y;
  const int tx = threadIdx.x & 31, ty = threadIdx.x >> 5;
  #pragma unroll
  for (int i = 0; i < 32; i += 8)
    t[ty + i][tx] = in[(long)(by * 32 + ty + i) * C + bx * 32 + tx];
  __syncthreads();
  #pragma unroll
  for (int i = 0; i < 32; i += 8)
    out[(long)(bx * 32 + ty + i) * R + by * 32 + tx] = (bf16)t[tx][ty + i];
}

// ---------------------------------------------------------------------------
__global__ __launch_bounds__(256) void rope_table_kernel(float* __restrict__ cosT,
                                                         float* __restrict__ sinT) {
  const int idx = blockIdx.x * 256 + threadIdx.x;
  const int i = idx & 63, s = idx >> 6;
  const float inv = powf(10000.f, -(float)i / 64.f);
  const float ang = (float)s * inv;
  cosT[idx] = cosf(ang);
  sinT[idx] = sinf(ang);
}

// ---------------------------------------------------------------------------
// RoPE apply + reorder: qkv [s][12288] -> q,k [h][s][128]
// ---------------------------------------------------------------------------
__global__ __launch_bounds__(256) void rope_kernel(
    const bf16* __restrict__ qkv,
    const float* __restrict__ cosT, const float* __restrict__ sinT,
    bf16* __restrict__ qout, bf16* __restrict__ kout) {
  const long idx = (long)blockIdx.x * 256 + threadIdx.x;  // 2048*32*64
  const int i = (int)(idx & 63);
  const int h = (int)((idx >> 6) & 31);
  const int s = (int)(idx >> 11);
  const long inq = (long)s * 12288 + h * 128 + i;
  const float c = cosT[s * 64 + i], sn = sinT[s * 64 + i];
  const long o1 = (long)h * 2048 * 128 + (long)s * 128 + i;
  const float q1 = (float)qkv[inq], q2 = (float)qkv[inq + 64];
  qout[o1]      = (bf16)(q1 * c - q2 * sn);
  qout[o1 + 64] = (bf16)(q2 * c + q1 * sn);
  const float k1 = (float)qkv[inq + 4096], k2 = (float)qkv[inq + 4096 + 64];
  kout[o1]      = (bf16)(k1 * c - k2 * sn);
  kout[o1 + 64] = (bf16)(k2 * c + k1 * sn);
}

// ---------------------------------------------------------------------------
// V reorder-transpose: qkv cols 8192.. -> vt [h][128][2048]
// ---------------------------------------------------------------------------
__global__ __launch_bounds__(256) void vtrans_kernel(const bf16* __restrict__ qkv,
                                                     bf16* __restrict__ vt) {
  __shared__ bf16 t[64][65];
  const int h = blockIdx.z;
  const int s0 = blockIdx.x * 64, d0 = blockIdx.y * 64;
  const int tx = threadIdx.x & 63, ty = threadIdx.x >> 6;
  #pragma unroll
  for (int i = 0; i < 64; i += 4)
    t[ty + i][tx] = qkv[(long)(s0 + ty + i) * 12288 + 8192 + h * 128 + d0 + tx];
  __syncthreads();
  #pragma unroll
  for (int i = 0; i < 64; i += 4)
    vt[(long)h * 128 * 2048 + (long)(d0 + ty + i) * 2048 + s0 + tx] = t[tx][ty + i];
}

// ---------------------------------------------------------------------------
// Flash attention, causal. Block=(qb,head), 4 waves x 16 q-rows.
// ---------------------------------------------------------------------------
__global__ __launch_bounds__(256) void attn_kernel(
    const bf16* __restrict__ qh, const bf16* __restrict__ kh,
    const bf16* __restrict__ vt, bf16* __restrict__ outb) {
  constexpr int S = 2048;
  const int qb = blockIdx.x, head = blockIdx.y;
  const int tid = threadIdx.x, wave = tid >> 6, lane = tid & 63;
  __shared__ bf16 Ks[64 * 128];
  __shared__ bf16 Vs[128 * 64];
  __shared__ bf16 Plds[4][16 * 64];
  const bf16* qhh = qh + (long)head * S * 128;
  const bf16* khh = kh + (long)head * S * 128;
  const bf16* vth = vt + (long)head * 128 * S;

  const int l15 = lane & 15, l4 = lane >> 4;
  const int qrow = qb * 64 + wave * 16 + l15;
  bf16x8 qf[4];
  #pragma unroll
  for (int kf = 0; kf < 4; ++kf)
    qf[kf] = *(const bf16x8*)(qhh + (long)qrow * 128 + kf * 32 + l4 * 8);

  float m_r[4], l_r[4];
  #pragma unroll
  for (int r = 0; r < 4; ++r) { m_r[r] = -INFINITY; l_r[r] = 0.f; }
  f32x4 oacc[8] = {};
  const float scale = 0.08838834764831845f;

  for (int tb = 0; tb <= qb; ++tb) {
    #pragma unroll
    for (int i = 0; i < 4; ++i) {
      const int c = wave + 4 * i;
      gload_lds16(khh + (long)(tb * 64 + c * 4 + l4) * 128 + l15 * 8, Ks + c * 512);
      gload_lds16(vth + (long)(c * 8 + (lane >> 3)) * S + tb * 64 + (lane & 7) * 8, Vs + c * 512);
    }
    __syncthreads();

    f32x4 sf[4];
    #pragma unroll
    for (int ft = 0; ft < 4; ++ft) {
      f32x4 acn = {};
      #pragma unroll
      for (int kf = 0; kf < 4; ++kf) {
        bf16x8 kfr = *(const bf16x8*)(Ks + (ft * 16 + l15) * 128 + kf * 32 + l4 * 8);
        acn = __builtin_amdgcn_mfma_f32_16x16x32_bf16(qf[kf], kfr, acn, 0, 0, 0);
      }
      #pragma unroll
      for (int r = 0; r < 4; ++r) sf[ft][r] = acn[r] * scale;
    }
    if (tb == qb) {
      #pragma unroll
      for (int ft = 0; ft < 4; ++ft) {
        const int t_l = ft * 16 + l15;
        #pragma unroll
        for (int r = 0; r < 4; ++r)
          if (t_l > wave * 16 + l4 * 4 + r) sf[ft][r] = -INFINITY;
      }
    }
    float scl[4];
    #pragma unroll
    for (int r = 0; r < 4; ++r) {
      float mx = fmaxf(fmaxf(sf[0][r], sf[1][r]), fmaxf(sf[2][r], sf[3][r]));
      mx = fmaxf(mx, __shfl_xor(mx, 1, 64));
      mx = fmaxf(mx, __shfl_xor(mx, 2, 64));
      mx = fmaxf(mx, __shfl_xor(mx, 4, 64));
      mx = fmaxf(mx, __shfl_xor(mx, 8, 64));
      const float mnew = fmaxf(m_r[r], mx);
      scl[r] = __expf(m_r[r] - mnew);
      m_r[r] = mnew;
      float rs = 0.f;
      #pragma unroll
      for (int ft = 0; ft < 4; ++ft) {
        const float pexp = __expf(sf[ft][r] - mnew);
        sf[ft][r] = pexp;
        rs += pexp;
      }
      rs += __shfl_xor(rs, 1, 64);
      rs += __shfl_xor(rs, 2, 64);
      rs += __shfl_xor(rs, 4, 64);
      rs += __shfl_xor(rs, 8, 64);
      l_r[r] = l_r[r] * scl[r] + rs;
    }
    #pragma unroll
    for (int ft = 0; ft < 4; ++ft)
      #pragma unroll
      for (int r = 0; r < 4; ++r)
        Plds[wave][(l4 * 4 + r) * 64 + ft * 16 + l15] = (bf16)sf[ft][r];
    #pragma unroll
    for (int fd = 0; fd < 8; ++fd)
      #pragma unroll
      for (int r = 0; r < 4; ++r) oacc[fd][r] *= scl[r];
    #pragma unroll
    for (int fd = 0; fd < 8; ++fd) {
      #pragma unroll
      for (int kt = 0; kt < 2; ++kt) {
        bf16x8 pa = *(const bf16x8*)(&Plds[wave][l15 * 64 + kt * 32 + l4 * 8]);
        bf16x8 vb = *(const bf16x8*)(Vs + (fd * 16 + l15) * 64 + kt * 32 + l4 * 8);
        oacc[fd] = __builtin_amdgcn_mfma_f32_16x16x32_bf16(pa, vb, oacc[fd], 0, 0, 0);
      }
    }
    __syncthreads();
  }
  #pragma unroll
  for (int fd = 0; fd < 8; ++fd) {
    #pragma unroll
    for (int r = 0; r < 4; ++r) {
      const long row = qb * 64 + wave * 16 + l4 * 4 + r;
      outb[row * 4096 + head * 128 + fd * 16 + l15] = (bf16)(oacc[fd][r] / l_r[r]);
    }
  }
}

// ---------------------------------------------------------------------------
// SwiGLU on fused x12 [2048][22016] (x1 = cols 0..11007, x2 = 11008..)
// ---------------------------------------------------------------------------
__global__ __launch_bounds__(256) void swiglu_kernel(
    const bf16* __restrict__ x12, bf16* __restrict__ g) {
  const int s = blockIdx.y;
  const int c = (blockIdx.x * 256 + threadIdx.x) * 8;
  if (c >= 11008) return;
  const bf16* row = x12 + (long)s * 22016;
  bf16x8 av = *(const bf16x8*)(row + c);
  bf16x8 bv = *(const bf16x8*)(row + 11008 + c);
  bf16x8 o;
  #pragma unroll
  for (int j = 0; j < 8; ++j) {
    const float v = (float)av[j];
    const float sg = v / (1.f + __expf(-v));
    o[j] = (bf16)(sg * (float)bv[j]);
  }
  *(bf16x8*)(g + (long)s * 11008 + c) = o;
}

// ---------------------------------------------------------------------------
extern "C" void kernel_launch(void* const* d_in, const int* in_sizes, int n_in,
                              void* d_out, int out_size, void* d_ws, size_t ws_size,
                              hipStream_t stream) {
  const float* X  = (const float*)d_in[0];
  const float* Wq = (const float*)d_in[1];
  const float* Wk = (const float*)d_in[2];
  const float* Wv = (const float*)d_in[3];
  const float* Wo = (const float*)d_in[4];
  const float* bo = (const float*)d_in[5];
  const float* g1 = (const float*)d_in[6];
  const float* g2 = (const float*)d_in[7];
  const float* W1 = (const float*)d_in[8];
  const float* W2 = (const float*)d_in[9];
  const float* W3 = (const float*)d_in[10];
  float* out = (float*)d_out;

  hipFuncSetAttribute((const void*)gemmd<256, 0>, hipFuncAttributeMaxDynamicSharedMemorySize, 131072);
  hipFuncSetAttribute((const void*)gemmd<128, 1>, hipFuncAttributeMaxDynamicSharedMemorySize, 98304);
  hipFuncSetAttribute((const void*)gemmd<128, 2>, hipFuncAttributeMaxDynamicSharedMemorySize, 98304);

  char* p = (char*)d_ws;
  auto alloc = [&](size_t bytes) {
    char* r = p;
    p += (bytes + 255) & ~(size_t)255;
    return r;
  };
  float* cosT = (float*)alloc(2048 * 64 * 4);
  float* sinT = (float*)alloc(2048 * 64 * 4);
  bf16* WqkvT = (bf16*)alloc(12288L * 4096 * 2);   // [12288][4096]
  bf16* WoT  = (bf16*)alloc(4096L * 4096 * 2);
  bf16* W12T = (bf16*)alloc(22016L * 4096 * 2);    // [22016][4096] (W1^T ; W2^T)
  bf16* W3T  = (bf16*)alloc(4096L * 11008 * 2);
  // BIG: phase 1 holds qkv(12288) + qh(4096) + kh(4096) + vt(4096) = 24576 cols;
  //      phase 2 holds x12 (22016 cols).  Size by the max: 24576.
  char* BIG  = alloc(2048L * 24576 * 2);
  bf16* hbuf = (bf16*)alloc(2048L * 4096 * 2);     // h, then attnb
  bf16* h2   = (bf16*)alloc(2048L * 4096 * 2);
  float* X2  = (float*)alloc(2048L * 4096 * 4);

  bf16* qkv = (bf16*)BIG;                 // [2048][12288]
  bf16* qhB = qkv + 2048L * 12288;        // [32][2048][128]
  bf16* khB = qhB + 2048L * 4096;
  bf16* vtB = khB + 2048L * 4096;
  bf16* x12 = (bf16*)BIG;                 // [2048][22016]
  bf16* gsw = (bf16*)WqkvT;               // reuse (dead after QKV GEMM): [2048][11008]
  bf16* attnb = hbuf;

  rope_table_kernel<<<512, 256, 0, stream>>>(cosT, sinT);
  wtrans_kernel<<<dim3(128, 128), 256, 0, stream>>>(Wq, WqkvT, 4096, 4096);
  wtrans_kernel<<<dim3(128, 128), 256, 0, stream>>>(Wk, WqkvT + 4096L * 4096, 4096, 4096);
  wtrans_kernel<<<dim3(128, 128), 256, 0, stream>>>(Wv, WqkvT + 2 * 4096L * 4096, 4096, 4096);
  wtrans_kernel<<<dim3(128, 128), 256, 0, stream>>>(Wo, WoT, 4096, 4096);
  wtrans_kernel<<<dim3(344, 128), 256, 0, stream>>>(W1, W12T, 4096, 11008);
  wtrans_kernel<<<dim3(344, 128), 256, 0, stream>>>(W2, W12T + 11008L * 4096, 4096, 11008);
  wtrans_kernel<<<dim3(128, 344), 256, 0, stream>>>(W3, W3T, 11008, 4096);

  rmsnorm_kernel<<<2048, 256, 0, stream>>>(X, g1, hbuf, 4096);

  // qkv = h @ [Wq|Wk|Wv]   (384 blocks, 256x256 tiles)
  gemmd<256, 0><<<384, 512, 131072, stream>>>(hbuf, WqkvT, qkv, nullptr, nullptr, 2048, 12288, 4096, 8);

  rope_kernel<<<16384, 256, 0, stream>>>(qkv, cosT, sinT, qhB, khB);
  vtrans_kernel<<<dim3(32, 2, 32), 256, 0, stream>>>(qkv, vtB);

  attn_kernel<<<dim3(32, 32), 256, 0, stream>>>(qhB, khB, vtB, attnb);

  // X2 = attn @ Wo + bo + X   (128x256 tiles -> 256 blocks, one full round)
  gemmd<128, 1><<<256, 512, 98304, stream>>>(attnb, WoT, X2, bo, X, 2048, 4096, 4096, 16);

  rmsnorm_kernel<<<2048, 256, 0, stream>>>(X2, g2, h2, 4096);

  // x12 = h2 @ [W1|W2]   (688 blocks, 256x256 tiles)
  gemmd<256, 0><<<688, 512, 131072, stream>>>(h2, W12T, x12, nullptr, nullptr, 2048, 22016, 4096, 8);

  swiglu_kernel<<<dim3(6, 2048), 256, 0, stream>>>(x12, gsw);

  // out = g @ W3 + X2   (128x256 tiles -> 256 blocks, K=11008)
  gemmd<128, 2><<<256, 512, 98304, stream>>>(gsw, W3T, out, nullptr, X2, 2048, 4096, 11008, 16);
}

// Round 5
// 1449.082 us; speedup vs baseline: 1.3328x; 1.0278x over previous
//
#include <hip/hip_runtime.h>
#include <hip/hip_bf16.h>
#include <cstdint>
#include <cmath>

typedef __bf16 bf16;
typedef __attribute__((ext_vector_type(8))) __bf16 bf16x8;
typedef __attribute__((ext_vector_type(4))) __bf16 bf16x4;
typedef __attribute__((ext_vector_type(4))) float f32x4;

// async global->LDS, 16B per lane, dest = wave-uniform base (+ lane*16 by HW)
__device__ __forceinline__ void gload_lds16(const void* g, void* l) {
  __builtin_amdgcn_global_load_lds((__attribute__((address_space(1))) void*)g,
                                   (__attribute__((address_space(3))) void*)l,
                                   16, 0, 0);
}

// ---------------------------------------------------------------------------
// Drift GEMM: BM x 256 tile, BK=64, 8 waves (4M x 2N: wave = BM/4 rows x 128
// cols), double-buffered LDS, ONE __syncthreads per K-tile, full-tile prefetch
// front-loaded. C = A[M,K] @ Bt^T (Bt stored [N][K] bf16).
// LDS: buf*BUFS + {A:0,B:ASZ} + row*128 + (chunk^(row&7))*16 (conflict-free).
// EPI 1: f32 = acc+bias[col]+resid       (Wo)
// EPI 2: f32 = acc+resid                 (W3)
// EPI 3: QKV fused RoPE + head reorder: q,k -> [h][s][128], v -> [h][128][s]
// EPI 4: FF fused SwiGLU on 16-interleaved W1/W2 -> g [s][11008]
// ---------------------------------------------------------------------------
template<int BM, int EPI>
__global__ __launch_bounds__(512, 2) void gemmd(
    const bf16* __restrict__ A, const bf16* __restrict__ Bt, void* __restrict__ Cv,
    const float* __restrict__ bias, const float* __restrict__ resid,
    const float* __restrict__ cosT, const float* __restrict__ sinT,
    bf16* __restrict__ q_out, bf16* __restrict__ k_out, bf16* __restrict__ v_out,
    int M, int N, int K, int gm) {
  extern __shared__ char lds[];
  constexpr int ASZ = BM * 128;      // A region bytes (BM rows x 128B)
  constexpr int BUFS = ASZ + 32768;  // per-buffer stride (B = 256 rows x 128B)
  constexpr int MF = BM / 64;        // m-frags per wave (wave rows = BM/4)
  constexpr int LA = BM / 64;        // A stage loads per thread

  const int tid = threadIdx.x;
  const int wave = tid >> 6, lane = tid & 63;
  const int wr = wave >> 1, wc = wave & 1;   // 4M x 2N wave grid
  const int l15 = lane & 15, l4 = lane >> 4;
  // XCD-aware swizzle (grids are multiples of 8)
  const int qq = gridDim.x >> 3;
  const int wgid = (blockIdx.x & 7) * qq + (blockIdx.x >> 3);
  const int tm = wgid % gm, tn = wgid / gm;
  const long brow = (long)tm * BM, bcol = (long)tn * 256;
  const int NT = K >> 6;
  const bf16* Ab = A + brow * K;
  const bf16* Bb = Bt + bcol * K;

  f32x4 acc[MF][8];
  #pragma unroll
  for (int i = 0; i < MF; ++i)
    #pragma unroll
    for (int j = 0; j < 8; ++j) acc[i][j] = (f32x4){0.f, 0.f, 0.f, 0.f};

  bf16x8 a[MF][2], b[8][2];

  auto stage = [&](int T) {
    const long kofs = (long)T << 6;
    char* wb = lds + (T & 1) * BUFS;
    #pragma unroll
    for (int i = 0; i < LA; ++i) {
      const int slot = i * 512 + tid, r = slot >> 3, c0 = slot & 7;
      gload_lds16(Ab + (long)r * K + kofs + ((c0 ^ (r & 7)) << 3), wb + slot * 16);
    }
    #pragma unroll
    for (int i = 0; i < 4; ++i) {
      const int slot = i * 512 + tid, r = slot >> 3, c0 = slot & 7;
      gload_lds16(Bb + (long)r * K + kofs + ((c0 ^ (r & 7)) << 3), wb + ASZ + slot * 16);
    }
  };

  stage(0);
  __syncthreads();

  for (int g = 0; g < NT; ++g) {
    const int pg = (g & 1) * BUFS;
    if (g + 1 < NT) stage(g + 1);   // writes opposite buffer; fenced by barrier
    #pragma unroll
    for (int nf = 0; nf < 8; ++nf)
      #pragma unroll
      for (int ks = 0; ks < 2; ++ks) {
        const int r = wc * 128 + nf * 16 + l15;
        b[nf][ks] = *(const bf16x8*)(lds + pg + ASZ + r * 128 + (((ks * 4 + l4) ^ (r & 7)) << 4));
      }
    #pragma unroll
    for (int mf = 0; mf < MF; ++mf)
      #pragma unroll
      for (int ks = 0; ks < 2; ++ks) {
        const int r = wr * (BM / 4) + mf * 16 + l15;
        a[mf][ks] = *(const bf16x8*)(lds + pg + r * 128 + (((ks * 4 + l4) ^ (r & 7)) << 4));
      }
    #pragma unroll
    for (int ks = 0; ks < 2; ++ks)
      #pragma unroll
      for (int mf = 0; mf < MF; ++mf)
        #pragma unroll
        for (int nf = 0; nf < 8; ++nf)
          acc[mf][nf] = __builtin_amdgcn_mfma_f32_16x16x32_bf16(
              a[mf][ks], b[nf][ks], acc[mf][nf], 0, 0, 0);
    __syncthreads();
  }

  // ------------------------------- epilogues -------------------------------
  if (EPI == 1 || EPI == 2) {
    #pragma unroll
    for (int mf = 0; mf < MF; ++mf) {
      const long row0 = brow + wr * (BM / 4) + mf * 16 + l4 * 4;
      #pragma unroll
      for (int nf = 0; nf < 8; ++nf) {
        const long col = bcol + wc * 128 + nf * 16 + l15;
        #pragma unroll
        for (int rj = 0; rj < 4; ++rj) {
          const long idx = (row0 + rj) * N + col;
          const float v = acc[mf][nf][rj];
          if (EPI == 1) ((float*)Cv)[idx] = v + bias[col] + resid[idx];
          else          ((float*)Cv)[idx] = v + resid[idx];
        }
      }
    }
  } else if (EPI == 3) {
    const int region = (int)(bcol >> 12);           // 0=Q, 1=K, 2=V
    const int hc = (int)(bcol & 4095) + wc * 128;   // head-space col base
    const int h = hc >> 7;
    if (region < 2) {
      bf16* dh = (region == 0 ? q_out : k_out) + (long)h * 2048 * 128;
      #pragma unroll
      for (int mf = 0; mf < MF; ++mf) {
        #pragma unroll
        for (int rj = 0; rj < 4; ++rj) {
          const int s = (int)brow + wr * (BM / 4) + mf * 16 + l4 * 4 + rj;
          const float* cr = cosT + s * 64;
          const float* sr = sinT + s * 64;
          #pragma unroll
          for (int nfp = 0; nfp < 4; ++nfp) {
            const int d = nfp * 16 + l15;
            const float c = cr[d], sn = sr[d];
            const float x1 = acc[mf][nfp][rj], x2 = acc[mf][nfp + 4][rj];
            dh[(long)s * 128 + d]      = (bf16)(x1 * c - x2 * sn);
            dh[(long)s * 128 + d + 64] = (bf16)(x2 * c + x1 * sn);
          }
        }
      }
    } else {
      bf16* dh = v_out + (long)h * 128 * 2048;
      #pragma unroll
      for (int mf = 0; mf < MF; ++mf) {
        const int s0 = (int)brow + wr * (BM / 4) + mf * 16 + l4 * 4;
        #pragma unroll
        for (int nf = 0; nf < 8; ++nf) {
          const int d = nf * 16 + l15;
          bf16x4 v;
          #pragma unroll
          for (int rj = 0; rj < 4; ++rj) v[rj] = (bf16)acc[mf][nf][rj];
          *(bf16x4*)(dh + (long)d * 2048 + s0) = v;
        }
      }
    }
  } else {  // EPI == 4: fused SwiGLU, interleaved W12 columns -> g [s][11008]
    #pragma unroll
    for (int mf = 0; mf < MF; ++mf) {
      #pragma unroll
      for (int rj = 0; rj < 4; ++rj) {
        const int s = (int)brow + wr * (BM / 4) + mf * 16 + l4 * 4 + rj;
        bf16* gr = (bf16*)Cv + (long)s * 11008;
        #pragma unroll
        for (int nfp = 0; nfp < 4; ++nfp) {
          const int col = (int)bcol + wc * 128 + nfp * 32 + l15;
          const int j = ((col >> 5) << 4) + l15;
          const float x1 = acc[mf][2 * nfp][rj], x2 = acc[mf][2 * nfp + 1][rj];
          const float sg = x1 / (1.f + __expf(-x1));
          gr[j] = (bf16)(sg * x2);
        }
      }
    }
  }
}

// ---------------------------------------------------------------------------
// RMSNorm: one block per row of [2048][4096] f32 -> bf16
// ---------------------------------------------------------------------------
__global__ __launch_bounds__(256) void rmsnorm_kernel(
    const float* __restrict__ X, const float* __restrict__ gamma,
    bf16* __restrict__ out, int D) {
  const int row = blockIdx.x;
  const float* xr = X + (long)row * D;
  float ss = 0.f;
  for (int i = threadIdx.x * 4; i < D; i += 1024) {
    float4 v = *(const float4*)(xr + i);
    ss += v.x * v.x + v.y * v.y + v.z * v.z + v.w * v.w;
  }
  #pragma unroll
  for (int off = 32; off; off >>= 1) ss += __shfl_down(ss, off, 64);
  __shared__ float wsum[4];
  if ((threadIdx.x & 63) == 0) wsum[threadIdx.x >> 6] = ss;
  __syncthreads();
  const float tot = wsum[0] + wsum[1] + wsum[2] + wsum[3];
  const float scale = rsqrtf(1e-7f + tot / (float)D);
  bf16* orow = out + (long)row * D;
  for (int i = threadIdx.x * 4; i < D; i += 1024) {
    float4 v = *(const float4*)(xr + i);
    float4 g = *(const float4*)(gamma + i);
    orow[i]     = (bf16)(v.x * scale * g.x);
    orow[i + 1] = (bf16)(v.y * scale * g.y);
    orow[i + 2] = (bf16)(v.z * scale * g.z);
    orow[i + 3] = (bf16)(v.w * scale * g.w);
  }
}

// ---------------------------------------------------------------------------
// Weight transpose + f32->bf16: in [R][C] f32 -> out [C][R] bf16. 64x64 tiles.
// ---------------------------------------------------------------------------
__global__ __launch_bounds__(256) void wtrans_kernel(
    const float* __restrict__ in, bf16* __restrict__ out, int R, int C) {
  __shared__ float t[64][65];
  const int bx = blockIdx.x, by = blockIdx.y;
  const int tx = threadIdx.x & 63, ty = threadIdx.x >> 6;  // 64 x 4
  #pragma unroll
  for (int i = 0; i < 64; i += 4)
    t[ty + i][tx] = in[(long)(by * 64 + ty + i) * C + bx * 64 + tx];
  __syncthreads();
  #pragma unroll
  for (int i = 0; i < 64; i += 4)
    out[(long)(bx * 64 + ty + i) * R + by * 64 + tx] = (bf16)t[tx][ty + i];
}

// ---------------------------------------------------------------------------
// W1/W2 interleaved transpose: in [4096][11008] f32, source col j ->
// out row ((j>>4)<<5) + off + (j&15)  (off: W1=0, W2=16), cols = k (4096 bf16)
// ---------------------------------------------------------------------------
__global__ __launch_bounds__(256) void w12trans_kernel(
    const float* __restrict__ in, bf16* __restrict__ out, int off) {
  __shared__ float t[32][33];
  const int bx = blockIdx.x, by = blockIdx.y;  // bx: j-tiles (344), by: k (128)
  const int tx = threadIdx.x & 31, ty = threadIdx.x >> 5;
  #pragma unroll
  for (int i = 0; i < 32; i += 8)
    t[ty + i][tx] = in[(long)(by * 32 + ty + i) * 11008 + bx * 32 + tx];
  __syncthreads();
  #pragma unroll
  for (int i = 0; i < 32; i += 8) {
    const int j = bx * 32 + ty + i;
    const int r = ((j >> 4) << 5) + off + (j & 15);
    out[(long)r * 4096 + by * 32 + tx] = (bf16)t[tx][ty + i];
  }
}

// ---------------------------------------------------------------------------
__global__ __launch_bounds__(256) void rope_table_kernel(float* __restrict__ cosT,
                                                         float* __restrict__ sinT) {
  const int idx = blockIdx.x * 256 + threadIdx.x;
  const int i = idx & 63, s = idx >> 6;
  const float inv = powf(10000.f, -(float)i / 64.f);
  const float ang = (float)s * inv;
  cosT[idx] = cosf(ang);
  sinT[idx] = sinf(ang);
}

// ---------------------------------------------------------------------------
// Flash attention, causal. Block=(qb,head), 4 waves x 16 q-rows.
// ---------------------------------------------------------------------------
__global__ __launch_bounds__(256) void attn_kernel(
    const bf16* __restrict__ qh, const bf16* __restrict__ kh,
    const bf16* __restrict__ vt, bf16* __restrict__ outb) {
  constexpr int S = 2048;
  const int qb = blockIdx.x, head = blockIdx.y;
  const int tid = threadIdx.x, wave = tid >> 6, lane = tid & 63;
  __shared__ bf16 Ks[64 * 128];
  __shared__ bf16 Vs[128 * 64];
  __shared__ bf16 Plds[4][16 * 64];
  const bf16* qhh = qh + (long)head * S * 128;
  const bf16* khh = kh + (long)head * S * 128;
  const bf16* vth = vt + (long)head * 128 * S;

  const int l15 = lane & 15, l4 = lane >> 4;
  const int qrow = qb * 64 + wave * 16 + l15;
  bf16x8 qf[4];
  #pragma unroll
  for (int kf = 0; kf < 4; ++kf)
    qf[kf] = *(const bf16x8*)(qhh + (long)qrow * 128 + kf * 32 + l4 * 8);

  float m_r[4], l_r[4];
  #pragma unroll
  for (int r = 0; r < 4; ++r) { m_r[r] = -INFINITY; l_r[r] = 0.f; }
  f32x4 oacc[8] = {};
  const float scale = 0.08838834764831845f;

  for (int tb = 0; tb <= qb; ++tb) {
    #pragma unroll
    for (int i = 0; i < 4; ++i) {
      const int c = wave + 4 * i;
      gload_lds16(khh + (long)(tb * 64 + c * 4 + l4) * 128 + l15 * 8, Ks + c * 512);
      gload_lds16(vth + (long)(c * 8 + (lane >> 3)) * S + tb * 64 + (lane & 7) * 8, Vs + c * 512);
    }
    __syncthreads();

    f32x4 sf[4];
    #pragma unroll
    for (int ft = 0; ft < 4; ++ft) {
      f32x4 acn = {};
      #pragma unroll
      for (int kf = 0; kf < 4; ++kf) {
        bf16x8 kfr = *(const bf16x8*)(Ks + (ft * 16 + l15) * 128 + kf * 32 + l4 * 8);
        acn = __builtin_amdgcn_mfma_f32_16x16x32_bf16(qf[kf], kfr, acn, 0, 0, 0);
      }
      #pragma unroll
      for (int r = 0; r < 4; ++r) sf[ft][r] = acn[r] * scale;
    }
    if (tb == qb) {
      #pragma unroll
      for (int ft = 0; ft < 4; ++ft) {
        const int t_l = ft * 16 + l15;
        #pragma unroll
        for (int r = 0; r < 4; ++r)
          if (t_l > wave * 16 + l4 * 4 + r) sf[ft][r] = -INFINITY;
      }
    }
    float scl[4];
    #pragma unroll
    for (int r = 0; r < 4; ++r) {
      float mx = fmaxf(fmaxf(sf[0][r], sf[1][r]), fmaxf(sf[2][r], sf[3][r]));
      mx = fmaxf(mx, __shfl_xor(mx, 1, 64));
      mx = fmaxf(mx, __shfl_xor(mx, 2, 64));
      mx = fmaxf(mx, __shfl_xor(mx, 4, 64));
      mx = fmaxf(mx, __shfl_xor(mx, 8, 64));
      const float mnew = fmaxf(m_r[r], mx);
      scl[r] = __expf(m_r[r] - mnew);
      m_r[r] = mnew;
      float rs = 0.f;
      #pragma unroll
      for (int ft = 0; ft < 4; ++ft) {
        const float pexp = __expf(sf[ft][r] - mnew);
        sf[ft][r] = pexp;
        rs += pexp;
      }
      rs += __shfl_xor(rs, 1, 64);
      rs += __shfl_xor(rs, 2, 64);
      rs += __shfl_xor(rs, 4, 64);
      rs += __shfl_xor(rs, 8, 64);
      l_r[r] = l_r[r] * scl[r] + rs;
    }
    #pragma unroll
    for (int ft = 0; ft < 4; ++ft)
      #pragma unroll
      for (int r = 0; r < 4; ++r)
        Plds[wave][(l4 * 4 + r) * 64 + ft * 16 + l15] = (bf16)sf[ft][r];
    #pragma unroll
    for (int fd = 0; fd < 8; ++fd)
      #pragma unroll
      for (int r = 0; r < 4; ++r) oacc[fd][r] *= scl[r];
    #pragma unroll
    for (int fd = 0; fd < 8; ++fd) {
      #pragma unroll
      for (int kt = 0; kt < 2; ++kt) {
        bf16x8 pa = *(const bf16x8*)(&Plds[wave][l15 * 64 + kt * 32 + l4 * 8]);
        bf16x8 vb = *(const bf16x8*)(Vs + (fd * 16 + l15) * 64 + kt * 32 + l4 * 8);
        oacc[fd] = __builtin_amdgcn_mfma_f32_16x16x32_bf16(pa, vb, oacc[fd], 0, 0, 0);
      }
    }
    __syncthreads();
  }
  #pragma unroll
  for (int fd = 0; fd < 8; ++fd) {
    #pragma unroll
    for (int r = 0; r < 4; ++r) {
      const long row = qb * 64 + wave * 16 + l4 * 4 + r;
      outb[row * 4096 + head * 128 + fd * 16 + l15] = (bf16)(oacc[fd][r] / l_r[r]);
    }
  }
}

// ---------------------------------------------------------------------------
extern "C" void kernel_launch(void* const* d_in, const int* in_sizes, int n_in,
                              void* d_out, int out_size, void* d_ws, size_t ws_size,
                              hipStream_t stream) {
  const float* X  = (const float*)d_in[0];
  const float* Wq = (const float*)d_in[1];
  const float* Wk = (const float*)d_in[2];
  const float* Wv = (const float*)d_in[3];
  const float* Wo = (const float*)d_in[4];
  const float* bo = (const float*)d_in[5];
  const float* g1 = (const float*)d_in[6];
  const float* g2 = (const float*)d_in[7];
  const float* W1 = (const float*)d_in[8];
  const float* W2 = (const float*)d_in[9];
  const float* W3 = (const float*)d_in[10];
  float* out = (float*)d_out;

  hipFuncSetAttribute((const void*)gemmd<256, 3>, hipFuncAttributeMaxDynamicSharedMemorySize, 131072);
  hipFuncSetAttribute((const void*)gemmd<256, 4>, hipFuncAttributeMaxDynamicSharedMemorySize, 131072);
  hipFuncSetAttribute((const void*)gemmd<128, 1>, hipFuncAttributeMaxDynamicSharedMemorySize, 98304);
  hipFuncSetAttribute((const void*)gemmd<128, 2>, hipFuncAttributeMaxDynamicSharedMemorySize, 98304);

  char* p = (char*)d_ws;
  auto alloc = [&](size_t bytes) {
    char* r = p;
    p += (bytes + 255) & ~(size_t)255;
    return r;
  };
  float* cosT = (float*)alloc(2048 * 64 * 4);
  float* sinT = (float*)alloc(2048 * 64 * 4);
  bf16* WqkvT = (bf16*)alloc(12288L * 4096 * 2);   // [12288][4096]; later g
  bf16* WoT  = (bf16*)alloc(4096L * 4096 * 2);
  bf16* W12T = (bf16*)alloc(22016L * 4096 * 2);    // interleaved [22016][4096]
  bf16* W3T  = (bf16*)alloc(4096L * 11008 * 2);
  bf16* qhB  = (bf16*)alloc(2048L * 4096 * 2);     // [32][2048][128]
  bf16* khB  = (bf16*)alloc(2048L * 4096 * 2);
  bf16* vtB  = (bf16*)alloc(2048L * 4096 * 2);     // [32][128][2048]
  bf16* hbuf = (bf16*)alloc(2048L * 4096 * 2);     // h, then attnb
  bf16* h2   = (bf16*)alloc(2048L * 4096 * 2);
  float* X2  = (float*)alloc(2048L * 4096 * 4);

  bf16* gsw = (bf16*)WqkvT;   // g [2048][11008] (WqkvT dead after QKV GEMM)
  bf16* attnb = hbuf;

  rope_table_kernel<<<512, 256, 0, stream>>>(cosT, sinT);
  wtrans_kernel<<<dim3(64, 64), 256, 0, stream>>>(Wq, WqkvT, 4096, 4096);
  wtrans_kernel<<<dim3(64, 64), 256, 0, stream>>>(Wk, WqkvT + 4096L * 4096, 4096, 4096);
  wtrans_kernel<<<dim3(64, 64), 256, 0, stream>>>(Wv, WqkvT + 2 * 4096L * 4096, 4096, 4096);
  wtrans_kernel<<<dim3(64, 64), 256, 0, stream>>>(Wo, WoT, 4096, 4096);
  w12trans_kernel<<<dim3(344, 128), 256, 0, stream>>>(W1, W12T, 0);
  w12trans_kernel<<<dim3(344, 128), 256, 0, stream>>>(W2, W12T, 16);
  wtrans_kernel<<<dim3(64, 172), 256, 0, stream>>>(W3, W3T, 11008, 4096);

  rmsnorm_kernel<<<2048, 256, 0, stream>>>(X, g1, hbuf, 4096);

  // q,k,v = rope/reorder(h @ [Wq|Wk|Wv])  — fused epilogue
  gemmd<256, 3><<<384, 512, 131072, stream>>>(hbuf, WqkvT, nullptr, nullptr, nullptr,
                                              cosT, sinT, qhB, khB, vtB,
                                              2048, 12288, 4096, 8);

  attn_kernel<<<dim3(32, 32), 256, 0, stream>>>(qhB, khB, vtB, attnb);

  // X2 = attn @ Wo + bo + X
  gemmd<128, 1><<<256, 512, 98304, stream>>>(attnb, WoT, X2, bo, X,
                                             nullptr, nullptr, nullptr, nullptr, nullptr,
                                             2048, 4096, 4096, 16);

  rmsnorm_kernel<<<2048, 256, 0, stream>>>(X2, g2, h2, 4096);

  // g = silu(h2@W1) * (h2@W2)  — fused epilogue on interleaved W12
  gemmd<256, 4><<<688, 512, 131072, stream>>>(h2, W12T, gsw, nullptr, nullptr,
                                              nullptr, nullptr, nullptr, nullptr, nullptr,
                                              2048, 22016, 4096, 8);

  // out = g @ W3 + X2
  gemmd<128, 2><<<256, 512, 98304, stream>>>(gsw, W3T, out, nullptr, X2,
                                             nullptr, nullptr, nullptr, nullptr, nullptr,
                                             2048, 4096, 11008, 16);
}